// Round 1
// baseline (569.174 us; speedup 1.0000x reference)
//
#include <hip/hip_runtime.h>
#include <math.h>

#define T_TOKENS 16384
#define D_DIM    2048
#define E_EXP    64
#define TOPK     8

// ---------------- Kernel 1: logits = x @ gw^T + bias ----------------
// grid 256 blocks x 512 threads. Block owns 64 tokens. Wave q (0..7) owns
// d-slice [q*16, q*16+16) of each 128-wide d-tile; lane = local token.
// gate_w addresses are wave-uniform -> scalar loads; inner loop ~pure v_fma_f32.

#define TPB     64              // tokens per block
#define NW      8               // waves per block
#define BLK1    (NW * 64)       // 512 threads
#define DTILE   128
#define NTILE   (D_DIM / DTILE) // 16
#define DSLICE  (DTILE / NW)    // 16 floats per wave per tile
#define XSTRIDE (DTILE + 4)     // 132 floats (528B, 16B-aligned rows)
#define RSTRIDE (E_EXP + 4)     // 68 floats (272B, 16B-aligned rows)

__global__ __launch_bounds__(BLK1, 2) void moe_logits_kernel(
    const float* __restrict__ x, const float* __restrict__ gw,
    const float* __restrict__ bias, float* __restrict__ logits,
    float* __restrict__ counts_zero)
{
  __shared__ float xlds[TPB * XSTRIDE];      // 33792 B
  __shared__ float red[4 * TPB * RSTRIDE];   // 69632 B

  const int tid = threadIdx.x;
  const int q   = __builtin_amdgcn_readfirstlane(tid >> 6);  // wave id, uniform
  const int tl  = tid & 63;                                  // lane = local token
  const int tok0 = blockIdx.x * TPB;

  if (blockIdx.x == 0 && tid < E_EXP) counts_zero[tid] = 0.0f;  // zero counts region

  float acc[E_EXP];
  #pragma unroll
  for (int e = 0; e < E_EXP; ++e) acc[e] = 0.0f;

  #pragma unroll 1
  for (int tile = 0; tile < NTILE; ++tile) {
    // ---- stage x tile [64 tokens x 128 d] into LDS, coalesced float4 ----
    {
      const float4* xg = (const float4*)x;
      #pragma unroll
      for (int p = 0; p < 4; ++p) {
        int fl  = p * BLK1 + tid;       // 0..2047 float4 slots
        int row = fl >> 5;              // 32 float4 per row
        int c4  = fl & 31;
        float4 v = xg[(size_t)(tok0 + row) * (D_DIM / 4) + (tile * DTILE) / 4 + c4];
        *(float4*)&xlds[row * XSTRIDE + c4 * 4] = v;
      }
    }
    __syncthreads();

    // ---- per-thread x fragment: 16 floats of my token, my wave's d-slice ----
    float xr[DSLICE];
    #pragma unroll
    for (int j = 0; j < DSLICE / 4; ++j) {
      float4 v = *(const float4*)&xlds[tl * XSTRIDE + q * DSLICE + j * 4];
      xr[j*4+0] = v.x; xr[j*4+1] = v.y; xr[j*4+2] = v.z; xr[j*4+3] = v.w;
    }

    // ---- 64 experts x 16 FMAs; gw address uniform per wave ----
    const float* gwp = gw + tile * DTILE + q * DSLICE;
    #pragma unroll 4
    for (int e = 0; e < E_EXP; ++e) {
      const float4* g4 = (const float4*)(gwp + (size_t)e * D_DIM);
      float4 g0 = g4[0], g1 = g4[1], g2 = g4[2], g3 = g4[3];
      float s = acc[e];
      s = fmaf(xr[0],  g0.x, s); s = fmaf(xr[1],  g0.y, s);
      s = fmaf(xr[2],  g0.z, s); s = fmaf(xr[3],  g0.w, s);
      s = fmaf(xr[4],  g1.x, s); s = fmaf(xr[5],  g1.y, s);
      s = fmaf(xr[6],  g1.z, s); s = fmaf(xr[7],  g1.w, s);
      s = fmaf(xr[8],  g2.x, s); s = fmaf(xr[9],  g2.y, s);
      s = fmaf(xr[10], g2.z, s); s = fmaf(xr[11], g2.w, s);
      s = fmaf(xr[12], g3.x, s); s = fmaf(xr[13], g3.y, s);
      s = fmaf(xr[14], g3.z, s); s = fmaf(xr[15], g3.w, s);
      acc[e] = s;
    }
    __syncthreads();
  }

  // ---- tree-reduce partial logits across the 8 waves via LDS ----
  // L1: waves 4..7 -> slabs 0..3; waves 0..3 add
  if (q >= 4) {
    float* r = &red[(q - 4) * TPB * RSTRIDE + tl * RSTRIDE];
    #pragma unroll
    for (int e = 0; e < E_EXP; e += 4)
      *(float4*)&r[e] = make_float4(acc[e], acc[e+1], acc[e+2], acc[e+3]);
  }
  __syncthreads();
  if (q < 4) {
    const float* r = &red[q * TPB * RSTRIDE + tl * RSTRIDE];
    #pragma unroll
    for (int e = 0; e < E_EXP; e += 4) {
      float4 v = *(const float4*)&r[e];
      acc[e] += v.x; acc[e+1] += v.y; acc[e+2] += v.z; acc[e+3] += v.w;
    }
  }
  __syncthreads();
  // L2: waves 2,3 -> slabs 0,1; waves 0,1 add
  if (q == 2 || q == 3) {
    float* r = &red[(q - 2) * TPB * RSTRIDE + tl * RSTRIDE];
    #pragma unroll
    for (int e = 0; e < E_EXP; e += 4)
      *(float4*)&r[e] = make_float4(acc[e], acc[e+1], acc[e+2], acc[e+3]);
  }
  __syncthreads();
  if (q < 2) {
    const float* r = &red[q * TPB * RSTRIDE + tl * RSTRIDE];
    #pragma unroll
    for (int e = 0; e < E_EXP; e += 4) {
      float4 v = *(const float4*)&r[e];
      acc[e] += v.x; acc[e+1] += v.y; acc[e+2] += v.z; acc[e+3] += v.w;
    }
  }
  __syncthreads();
  // L3: wave 1 -> slab 0; wave 0 adds, then parks final in slab 0
  if (q == 1) {
    float* r = &red[tl * RSTRIDE];
    #pragma unroll
    for (int e = 0; e < E_EXP; e += 4)
      *(float4*)&r[e] = make_float4(acc[e], acc[e+1], acc[e+2], acc[e+3]);
  }
  __syncthreads();
  if (q == 0) {
    float* r = &red[tl * RSTRIDE];
    #pragma unroll
    for (int e = 0; e < E_EXP; e += 4) {
      float4 v = *(const float4*)&r[e];
      *(float4*)&r[e] = make_float4(acc[e] + v.x, acc[e+1] + v.y,
                                    acc[e+2] + v.z, acc[e+3] + v.w);
    }
  }
  __syncthreads();

  // ---- cooperative coalesced store with bias: 64 tokens x 64 experts ----
  #pragma unroll
  for (int p = 0; p < 2; ++p) {
    int fl  = p * BLK1 + tid;   // 0..1023 float4 slots
    int row = fl >> 4;          // 16 float4 per row
    int c   = fl & 15;
    float4 v = *(const float4*)&red[row * RSTRIDE + c * 4];
    float4 b = *(const float4*)&bias[c * 4];
    v.x += b.x; v.y += b.y; v.z += b.z; v.w += b.w;
    *(float4*)&logits[(size_t)(tok0 + row) * E_EXP + c * 4] = v;
  }
}

// ---------------- Kernel 2: top-8 + softmax + counts ----------------
__global__ __launch_bounds__(256) void topk_kernel(
    const float* __restrict__ logits, float* __restrict__ out)
{
  __shared__ unsigned hist[E_EXP];
  const int tid = threadIdx.x;
  const int t = blockIdx.x * 256 + tid;
  if (tid < E_EXP) hist[tid] = 0;
  __syncthreads();

  float l[E_EXP];
  const float4* lg = (const float4*)(logits + (size_t)t * E_EXP);
  #pragma unroll
  for (int j = 0; j < E_EXP / 4; ++j) {
    float4 v = lg[j];
    l[4*j] = v.x; l[4*j+1] = v.y; l[4*j+2] = v.z; l[4*j+3] = v.w;
  }

  float tv[TOPK]; int tix[TOPK];
  unsigned long long used = 0ull;
  #pragma unroll
  for (int k = 0; k < TOPK; ++k) {
    float best = -INFINITY; int bi = 0;
    #pragma unroll
    for (int j = 0; j < E_EXP; ++j) {
      bool ok = (((used >> j) & 1ull) == 0ull) && (l[j] > best);  // strict >: lowest index wins ties
      best = ok ? l[j] : best;
      bi   = ok ? j : bi;
    }
    tv[k] = best; tix[k] = bi;
    used |= (1ull << bi);
  }

  // softmax over the 8 (tv[0] is the max)
  float m = tv[0], s = 0.0f, w[TOPK];
  #pragma unroll
  for (int k = 0; k < TOPK; ++k) { w[k] = expf(tv[k] - m); s += w[k]; }
  float inv = 1.0f / s;

  #pragma unroll
  for (int k = 0; k < TOPK; ++k) {
    out[(size_t)t * TOPK + k] = (float)tix[k];                       // indices as fp32
    out[(size_t)T_TOKENS * TOPK + (size_t)t * TOPK + k] = w[k] * inv; // weights
  }

  #pragma unroll
  for (int k = 0; k < TOPK; ++k) atomicAdd(&hist[tix[k]], 1u);
  __syncthreads();
  if (tid < E_EXP)
    atomicAdd(&out[2 * (size_t)T_TOKENS * TOPK + tid], (float)hist[tid]);
}

extern "C" void kernel_launch(void* const* d_in, const int* in_sizes, int n_in,
                              void* d_out, int out_size, void* d_ws, size_t ws_size,
                              hipStream_t stream) {
  const float* x    = (const float*)d_in[0];
  const float* gw   = (const float*)d_in[1];
  const float* bias = (const float*)d_in[2];
  float* out    = (float*)d_out;
  float* logits = (float*)d_ws;   // 16384*64*4 = 4 MB scratch

  moe_logits_kernel<<<dim3(T_TOKENS / TPB), dim3(BLK1), 0, stream>>>(
      x, gw, bias, logits, out + 2 * (size_t)T_TOKENS * TOPK);
  topk_kernel<<<dim3(T_TOKENS / 256), dim3(256), 0, stream>>>(logits, out);
}

// Round 2
// 246.648 us; speedup vs baseline: 2.3076x; 2.3076x over previous
//
#include <hip/hip_runtime.h>
#include <math.h>

#define T_TOKENS 16384
#define D_DIM    2048
#define E_EXP    64
#define TOPK     8

// ---------------- Kernel 1: partial logits GEMM ----------------
// grid (T/64, NS). Block: 256 threads, tile 64 tokens x 64 experts,
// K-slice of D/NS, staged in Kc=64 LDS chunks.
// LDS: xl[t][k] stride 69 (2-way max), gl[k][e] stride 68 (float4-aligned reads).
// Thread tile 4 tok x 4 exp: per k = 4 ds_read_b32 + 1 ds_read_b128 + 16 v_fma.

#define TT   64                 // tokens per block
#define KC   64                 // k chunk
#define XS   69                 // xl row stride (pad: bank-safe, see analysis)
#define GS   68                 // gl row stride (pad + 16B aligned)

__global__ __launch_bounds__(256, 4) void moe_logits_kernel(
    const float* __restrict__ x, const float* __restrict__ gw,
    float* __restrict__ part, float* __restrict__ counts_zero, int ns)
{
  __shared__ float xl[TT * XS];   // 17664 B
  __shared__ float gl[KC * GS];   // 17408 B

  const int tid  = threadIdx.x;
  const int ks   = blockIdx.y;
  const int tok0 = blockIdx.x * TT;
  const int ksz  = D_DIM / ns;
  const int k0   = ks * ksz;
  const int nchunk = ksz / KC;

  if (blockIdx.x == 0 && ks == 0 && tid < E_EXP) counts_zero[tid] = 0.0f;

  // staging maps
  const int sf4 = tid & 15;      // float4 index along k (16 x 4 floats = 64)
  const int str = tid >> 4;      // token row 0..15 (4 rows of 16)
  const int sge = tid >> 2;      // expert 0..63
  const int sgk = tid & 3;       // k quarter 0..3

  // compute maps
  const int tg = tid & 15;       // token group: tokens tg*4..tg*4+3
  const int eg = tid >> 4;       // expert group: experts eg*4..eg*4+3

  float4 acc[4];
  #pragma unroll
  for (int j = 0; j < 4; ++j) acc[j] = make_float4(0.f, 0.f, 0.f, 0.f);

  #pragma unroll 1
  for (int c = 0; c < nchunk; ++c) {
    const int kc0 = k0 + c * KC;

    // ---- stage x: 64 tok x 64 k, coalesced float4 global, scalar LDS writes ----
    #pragma unroll
    for (int r = 0; r < 4; ++r) {
      const int t = str + 16 * r;
      float4 v = *(const float4*)&x[(size_t)(tok0 + t) * D_DIM + kc0 + sf4 * 4];
      xl[t * XS + sf4 * 4 + 0] = v.x;
      xl[t * XS + sf4 * 4 + 1] = v.y;
      xl[t * XS + sf4 * 4 + 2] = v.z;
      xl[t * XS + sf4 * 4 + 3] = v.w;
    }
    // ---- stage gw: 64 e x 64 k, transpose to gl[k][e] ----
    #pragma unroll
    for (int j4 = 0; j4 < 4; ++j4) {
      const int kk = sgk * 16 + j4 * 4;
      float4 v = *(const float4*)&gw[(size_t)sge * D_DIM + kc0 + kk];
      gl[(kk + 0) * GS + sge] = v.x;
      gl[(kk + 1) * GS + sge] = v.y;
      gl[(kk + 2) * GS + sge] = v.z;
      gl[(kk + 3) * GS + sge] = v.w;
    }
    __syncthreads();

    // ---- compute: 64 k x (4 tok x 4 exp) ----
    #pragma unroll 4
    for (int k = 0; k < KC; ++k) {
      float4 g = *(const float4*)&gl[k * GS + eg * 4];
      float x0 = xl[(tg * 4 + 0) * XS + k];
      float x1 = xl[(tg * 4 + 1) * XS + k];
      float x2 = xl[(tg * 4 + 2) * XS + k];
      float x3 = xl[(tg * 4 + 3) * XS + k];
      acc[0].x = fmaf(x0, g.x, acc[0].x); acc[0].y = fmaf(x0, g.y, acc[0].y);
      acc[0].z = fmaf(x0, g.z, acc[0].z); acc[0].w = fmaf(x0, g.w, acc[0].w);
      acc[1].x = fmaf(x1, g.x, acc[1].x); acc[1].y = fmaf(x1, g.y, acc[1].y);
      acc[1].z = fmaf(x1, g.z, acc[1].z); acc[1].w = fmaf(x1, g.w, acc[1].w);
      acc[2].x = fmaf(x2, g.x, acc[2].x); acc[2].y = fmaf(x2, g.y, acc[2].y);
      acc[2].z = fmaf(x2, g.z, acc[2].z); acc[2].w = fmaf(x2, g.w, acc[2].w);
      acc[3].x = fmaf(x3, g.x, acc[3].x); acc[3].y = fmaf(x3, g.y, acc[3].y);
      acc[3].z = fmaf(x3, g.z, acc[3].z); acc[3].w = fmaf(x3, g.w, acc[3].w);
    }
    __syncthreads();
  }

  // ---- store partials: part[ks][tok][e] ----
  #pragma unroll
  for (int j = 0; j < 4; ++j) {
    const size_t t = (size_t)tok0 + tg * 4 + j;
    *(float4*)&part[((size_t)ks * T_TOKENS + t) * E_EXP + eg * 4] = acc[j];
  }
}

// ---------------- Kernel 2: reduce partials + bias, top-8, softmax, counts ----
__global__ __launch_bounds__(256) void topk_kernel(
    const float* __restrict__ part, const float* __restrict__ bias,
    float* __restrict__ out, int ns)
{
  __shared__ unsigned hist[E_EXP];
  const int tid = threadIdx.x;
  const int t = blockIdx.x * 256 + tid;
  if (tid < E_EXP) hist[tid] = 0;
  __syncthreads();

  float l[E_EXP];
  #pragma unroll
  for (int j = 0; j < E_EXP / 4; ++j) {
    float4 b = *(const float4*)&bias[j * 4];
    l[4*j] = b.x; l[4*j+1] = b.y; l[4*j+2] = b.z; l[4*j+3] = b.w;
  }
  for (int ks = 0; ks < ns; ++ks) {
    const float4* p = (const float4*)&part[((size_t)ks * T_TOKENS + t) * E_EXP];
    #pragma unroll
    for (int j = 0; j < E_EXP / 4; ++j) {
      float4 v = p[j];
      l[4*j] += v.x; l[4*j+1] += v.y; l[4*j+2] += v.z; l[4*j+3] += v.w;
    }
  }

  float tv[TOPK]; int tix[TOPK];
  unsigned long long used = 0ull;
  #pragma unroll
  for (int k = 0; k < TOPK; ++k) {
    float best = -INFINITY; int bi = 0;
    #pragma unroll
    for (int j = 0; j < E_EXP; ++j) {
      bool ok = (((used >> j) & 1ull) == 0ull) && (l[j] > best);  // strict >: lowest index wins ties
      best = ok ? l[j] : best;
      bi   = ok ? j : bi;
    }
    tv[k] = best; tix[k] = bi;
    used |= (1ull << bi);
  }

  float m = tv[0], s = 0.0f, w[TOPK];
  #pragma unroll
  for (int k = 0; k < TOPK; ++k) { w[k] = expf(tv[k] - m); s += w[k]; }
  float inv = 1.0f / s;

  #pragma unroll
  for (int k = 0; k < TOPK; ++k) {
    out[(size_t)t * TOPK + k] = (float)tix[k];                        // indices as fp32
    out[(size_t)T_TOKENS * TOPK + (size_t)t * TOPK + k] = w[k] * inv; // weights
  }

  #pragma unroll
  for (int k = 0; k < TOPK; ++k) atomicAdd(&hist[tix[k]], 1u);
  __syncthreads();
  if (tid < E_EXP)
    atomicAdd(&out[2 * (size_t)T_TOKENS * TOPK + tid], (float)hist[tid]);
}

extern "C" void kernel_launch(void* const* d_in, const int* in_sizes, int n_in,
                              void* d_out, int out_size, void* d_ws, size_t ws_size,
                              hipStream_t stream) {
  const float* x    = (const float*)d_in[0];
  const float* gw   = (const float*)d_in[1];
  const float* bias = (const float*)d_in[2];
  float* out  = (float*)d_out;
  float* part = (float*)d_ws;

  const size_t slice_bytes = (size_t)T_TOKENS * E_EXP * sizeof(float);  // 4 MB
  int ns = 1;
  if (ws_size >= 4 * slice_bytes)      ns = 4;   // 16 MB scratch
  else if (ws_size >= 2 * slice_bytes) ns = 2;

  moe_logits_kernel<<<dim3(T_TOKENS / TT, ns), dim3(256), 0, stream>>>(
      x, gw, part, out + 2 * (size_t)T_TOKENS * TOPK, ns);
  topk_kernel<<<dim3(T_TOKENS / 256), dim3(256), 0, stream>>>(part, bias, out, ns);
}